// Round 3
// baseline (855.404 us; speedup 1.0000x reference)
//
#include <hip/hip_runtime.h>
#include <math.h>

typedef __attribute__((ext_vector_type(8))) short short8;
typedef __attribute__((ext_vector_type(4))) float f32x4;

// fp32 -> bf16 bits, round-to-nearest-even
static __device__ __forceinline__ unsigned short f2bf(float f) {
  unsigned int u = __float_as_uint(f);
  u = u + 0x7fffu + ((u >> 16) & 1u);
  return (unsigned short)(u >> 16);
}

// ---------------- kernel 1: supT[batch][col][n] (bf16) = (x @ W)^T ----------------
__global__ __launch_bounds__(256) void support_kernel(
    const float* __restrict__ x, const float* __restrict__ w,
    unsigned short* __restrict__ supT, int N) {
  __shared__ float aT[64][65];
  __shared__ float bs[64][132];

  const int tid = threadIdx.x;
  const long long r0 = (long long)blockIdx.x * 64;
  const float* Ab = x + r0 * 128;
  const int tx = tid & 15;
  const int ty = tid >> 4;

  float acc[4][8] = {};
  const int ar = tid & 63, ak = (tid >> 6) * 16;
  const int bk = tid >> 2, bc = (tid & 3) * 32;

  for (int k0 = 0; k0 < 128; k0 += 64) {
    const float4* asrc = (const float4*)(Ab + (long long)ar * 128 + k0 + ak);
    #pragma unroll
    for (int j = 0; j < 4; ++j) {
      float4 v = asrc[j];
      aT[ak + 4*j + 0][ar] = v.x;
      aT[ak + 4*j + 1][ar] = v.y;
      aT[ak + 4*j + 2][ar] = v.z;
      aT[ak + 4*j + 3][ar] = v.w;
    }
    const float4* bsrc = (const float4*)(w + (long long)(k0 + bk) * 128 + bc);
    #pragma unroll
    for (int j = 0; j < 8; ++j) *(float4*)&bs[bk][bc + 4*j] = bsrc[j];
    __syncthreads();
    #pragma unroll 16
    for (int k = 0; k < 64; ++k) {
      float a[4], b[8];
      *(float4*)a      = *(const float4*)&aT[k][ty*4];
      *(float4*)&b[0]  = *(const float4*)&bs[k][tx*8];
      *(float4*)&b[4]  = *(const float4*)&bs[k][tx*8 + 4];
      #pragma unroll
      for (int i = 0; i < 4; ++i)
        #pragma unroll
        for (int j = 0; j < 8; ++j)
          acc[i][j] = fmaf(a[i], b[j], acc[i][j]);
    }
    __syncthreads();
  }
  const int batch = (int)(r0 / N);
  const int nloc = (int)(r0 % N) + ty * 4;
  #pragma unroll
  for (int j = 0; j < 8; ++j) {
    const int col = tx * 8 + j;
    ushort4 pv;
    pv.x = f2bf(acc[0][j]); pv.y = f2bf(acc[1][j]);
    pv.z = f2bf(acc[2][j]); pv.w = f2bf(acc[3][j]);
    *(ushort4*)&supT[(size_t)batch * 128 * N + (size_t)col * N + nloc] = pv;
  }
}

// ---------------- kernel 2: out = LIF(adj @ support + bias) ----------------
// 16 rows x 128 cols per block, BK=128, grid 1024 (4 blocks/CU, 16 waves/CU).
// Double-buffered LDS A-tile, ONE barrier per K-iter, register prefetch of the
// next A-tile issued at top of body (HBM latency hides behind B-loads + MFMA).
// B (supT, 4 MB, L2-resident) fragments go global->reg, no LDS.
#define BK 128
#define ASTR 136   // shorts; 272 B row stride -> 2-way-max (free) bank aliasing

__global__ __launch_bounds__(256, 4) void spike_gemm_kernel(
    const float* __restrict__ adj, const unsigned short* __restrict__ supT,
    const float* __restrict__ bias, const int* __restrict__ tsp,
    float* __restrict__ out, int N) {
  __shared__ __align__(16) short As[2][16][ASTR];  // 8704 B total

  const int tid = threadIdx.x;
  const int lane = tid & 63;
  const int wave = tid >> 6;            // wave w -> cols w*32..+31
  const int batch = blockIdx.y;
  const int n0 = blockIdx.x * 16;

  const float* Ab = adj + ((size_t)batch * N + n0) * N;
  const unsigned short* Bb = supT + (size_t)batch * 128 * N;

  // A staging: thread -> row tid>>4, k-chunk (tid&15)*8
  const int ar = tid >> 4;
  const int ac = (tid & 15) * 8;
  const float* aRow = Ab + (size_t)ar * N + ac;

  // MFMA fragment coords
  const int fm = lane & 15;
  const int kg = lane >> 4;
  const unsigned short* b0 = Bb + (size_t)(wave * 32 + fm) * N + kg * 8;
  const unsigned short* b1 = b0 + (size_t)16 * N;

  f32x4 acc[2] = {};

  const int NIT = N / BK;

  // ---- prologue: stage A tile 0 into buf 0 ----
  {
    float4 v0 = *(const float4*)(aRow);
    float4 v1 = *(const float4*)(aRow + 4);
    short8 pk;
    pk[0] = (short)f2bf(v0.x); pk[1] = (short)f2bf(v0.y);
    pk[2] = (short)f2bf(v0.z); pk[3] = (short)f2bf(v0.w);
    pk[4] = (short)f2bf(v1.x); pk[5] = (short)f2bf(v1.y);
    pk[6] = (short)f2bf(v1.z); pk[7] = (short)f2bf(v1.w);
    *(short8*)&As[0][ar][ac] = pk;
  }

  for (int it = 0; it < NIT; ++it) {
    __syncthreads();
    const int cur = it & 1;
    const int k0 = it * BK;

    // ---- prefetch next A tile into registers (longest latency: issue first) ----
    float4 p0, p1;
    if (it + 1 < NIT) {
      p0 = *(const float4*)(aRow + k0 + BK);
      p1 = *(const float4*)(aRow + k0 + BK + 4);
    }

    // ---- B fragments for this iter: global(L2)->reg ----
    uint4 bfr[2][4];
    #pragma unroll
    for (int ks = 0; ks < 4; ++ks) {
      bfr[0][ks] = *(const uint4*)(b0 + k0 + ks * 32);
      bfr[1][ks] = *(const uint4*)(b1 + k0 + ks * 32);
    }

    // ---- MFMA over the staged tile ----
    #pragma unroll
    for (int ks = 0; ks < 4; ++ks) {
      short8 a = *(const short8*)&As[cur][fm][ks * 32 + kg * 8];
      acc[0] = __builtin_amdgcn_mfma_f32_16x16x32_bf16(a, *(const short8*)&bfr[0][ks], acc[0], 0, 0, 0);
      acc[1] = __builtin_amdgcn_mfma_f32_16x16x32_bf16(a, *(const short8*)&bfr[1][ks], acc[1], 0, 0, 0);
    }

    // ---- store prefetched tile to the other buffer ----
    if (it + 1 < NIT) {
      short8 pk;
      pk[0] = (short)f2bf(p0.x); pk[1] = (short)f2bf(p0.y);
      pk[2] = (short)f2bf(p0.z); pk[3] = (short)f2bf(p0.w);
      pk[4] = (short)f2bf(p1.x); pk[5] = (short)f2bf(p1.y);
      pk[6] = (short)f2bf(p1.z); pk[7] = (short)f2bf(p1.w);
      *(short8*)&As[cur ^ 1][ar][ac] = pk;
    }
  }

  // ---- epilogue: adaptive-LIF recurrence, exact reference op order ----
  const int T = *tsp;
  #pragma unroll
  for (int ct = 0; ct < 2; ++ct) {
    const int col = wave * 32 + ct * 16 + fm;
    const float bv = bias[col];
    #pragma unroll
    for (int i = 0; i < 4; ++i) {
      float I = acc[ct][i] + bv;
      float v = 0.0f, th = 1.0f, sacc = 0.0f;
      for (int t = 0; t < T; ++t) {
        v = v * 0.95f + I;                       // 1 - 1/tau_mem
        float u = v - th;
        float sig = 1.0f / (1.0f + expf(-4.0f * u));
        float hard = (u >= 0.0f) ? 1.0f : 0.0f;
        float s = (hard - sig) + sig;            // straight-through fwd
        sacc += s;
        v = v * (1.0f - s);
        th = th + (1.0f - th) / 60.0f + 0.1f * s;
      }
      const int row = n0 + kg * 4 + i;
      out[((size_t)batch * N + row) * 128 + col] = sacc / (float)T;
    }
  }
}

extern "C" void kernel_launch(void* const* d_in, const int* in_sizes, int n_in,
                              void* d_out, int out_size, void* d_ws, size_t ws_size,
                              hipStream_t stream) {
  const float* x    = (const float*)d_in[0];
  const float* adj  = (const float*)d_in[1];
  const float* w    = (const float*)d_in[2];
  const float* bias = (const float*)d_in[3];
  const int*   tsp  = (const int*)d_in[4];
  float* out = (float*)d_out;
  unsigned short* supT = (unsigned short*)d_ws;  // 4 MB

  const long long sz_x = in_sizes[0];
  const long long sz_adj = in_sizes[1];
  const int N = (int)(sz_adj / sz_x * 128);
  const int B = (int)(sz_x / ((long long)N * 128));
  const int rows = B * N;

  support_kernel<<<rows / 64, 256, 0, stream>>>(x, w, supT, N);
  spike_gemm_kernel<<<dim3(N / 16, B), 256, 0, stream>>>(adj, supT, bias, tsp, out, N);
}